// Round 7
// baseline (213.938 us; speedup 1.0000x reference)
//
#include <hip/hip_runtime.h>
#include <math.h>

#define YD 512
#define XD 64
#define KK 16
#define SS 10

typedef __attribute__((ext_vector_type(8))) short short8;
typedef __attribute__((ext_vector_type(4))) float f32x4;

__device__ __forceinline__ float wave_sum(float v) {
#pragma unroll
    for (int off = 32; off > 0; off >>= 1) v += __shfl_xor(v, off, 64);
    return v;
}

__device__ __forceinline__ float fast_rcp(float x) {
    return __builtin_amdgcn_rcpf(x);
}

__device__ __forceinline__ float bcast(float v, int l) {
    return __uint_as_float((unsigned int)__builtin_amdgcn_readlane((int)__float_as_uint(v), l));
}

__device__ __forceinline__ float softplusf(float x) {
    return fmaxf(x, 0.0f) + __logf(1.0f + __expf(-fabsf(x)));
}

__device__ __forceinline__ unsigned short f32_to_bf16(float f) {
    union { float f; unsigned int u; } v; v.f = f;
    unsigned int r = v.u + 0x7fffu + ((v.u >> 16) & 1u);
    return (unsigned short)(r >> 16);
}

__device__ __forceinline__ unsigned int pack2_bf16(float a, float b) {
    unsigned int ua = __float_as_uint(a), ub = __float_as_uint(b);
    ua = (ua + 0x7fffu + ((ua >> 16) & 1u)) >> 16;
    ub = (ub + 0x7fffu + ((ub >> 16) & 1u)) & 0xffff0000u;
    return ua | ub;
}

// ---------------- Kernel 0: prep ----------------
__global__ __launch_bounds__(256) void prep_kernel(
    const float* __restrict__ Wd_mu, const float* __restrict__ Wd_sig,
    const float* __restrict__ We_mu, const float* __restrict__ We_sig,
    const float* __restrict__ phi_mus, const float* __restrict__ phi_sigs,
    const float* __restrict__ theta_mus, const float* __restrict__ theta_sigs,
    const float* __restrict__ theta_logits,
    unsigned short* __restrict__ wmu_s, unsigned short* __restrict__ wsg_s,
    unsigned short* __restrict__ wenc,
    float4* __restrict__ tab4, float* __restrict__ lsetp)
{
    int idx = blockIdx.x * 256 + threadIdx.x;
    if (idx < 65536) {
        int mat = idx >> 15;            // 0: mu, 1: sig
        int e = idx & 32767;
        int j = e & 7;
        int n = (e >> 3) & 15;
        int q = (e >> 7) & 7;
        int tg = e >> 10;
        int k = q * 8 + j;
        int col = tg * 16 + n;
        const float* W = mat ? Wd_sig : Wd_mu;
        unsigned short* o = mat ? wsg_s : wmu_s;
        o[e] = f32_to_bf16(W[k * YD + col]);
    } else if (idx < 131072) {
        int ii = idx - 65536;
        int mat = ii >> 15;             // 0: We_mu, 1: We_sig
        int e = ii & 32767;
        int j = e & 7;
        int n = (e >> 3) & 15;
        int q = (e >> 7) & 3;
        int ct = (e >> 9) & 3;
        int kt = e >> 11;
        int k = kt * 32 + q * 8 + j;    // 0..511
        int col = ct * 16 + n;          // 0..63
        const float* W = mat ? We_sig : We_mu;
        wenc[mat * 32768 + e] = f32_to_bf16(W[k * XD + col]);
    } else if (idx < 131072 + 1024) {
        int e = idx - 131072;
        float4 t;
        t.x = phi_mus[e];
        t.y = phi_sigs[e];
        t.z = theta_mus[e];
        t.w = theta_sigs[e];
        tab4[e] = t;
    } else if (idx == 131072 + 1024) {
        float mt = theta_logits[0];
        for (int k = 1; k < KK; ++k) mt = fmaxf(mt, theta_logits[k]);
        float st = 0.f;
        for (int k = 0; k < KK; ++k) st += __expf(theta_logits[k] - mt);
        lsetp[0] = mt + __logf(st);
    }
}

// ---------------- Kernel 1: encoder via bf16 MFMA ----------------
__global__ __launch_bounds__(256) void encoder_mfma(
    const float* __restrict__ Y,
    const unsigned short* __restrict__ wenc,  // [2][32768] swizzled bf16
    const float* __restrict__ be_mu, const float* __restrict__ be_sig,
    float* __restrict__ enc_mu, float* __restrict__ enc_sig)
{
    const int t = threadIdx.x;
    const int w = t >> 6, lane = t & 63, l16 = lane & 15, quad = lane >> 4;
    const int mat = blockIdx.x & 1;
    const int rt = blockIdx.x >> 1;            // 16-row tile
    const int row = rt * 16 + l16;
    const int ct = w;                          // col tile 0..3
    const unsigned short* Ws = wenc + mat * 32768;
    const float4* Yrow = (const float4*)(Y + (size_t)row * YD);

    const float* bias = mat ? be_sig : be_mu;
    float* outp = mat ? enc_sig : enc_mu;
    const int col = ct * 16 + l16;
    const float bv = bias[col];
    f32x4 acc = (f32x4){bv, bv, bv, bv};

#pragma unroll
    for (int kt = 0; kt < 16; ++kt) {
        float4 y0 = Yrow[kt * 8 + quad * 2];
        float4 y1 = Yrow[kt * 8 + quad * 2 + 1];
        union { short8 s; unsigned int u[4]; } a;
        a.u[0] = pack2_bf16(y0.x, y0.y);
        a.u[1] = pack2_bf16(y0.z, y0.w);
        a.u[2] = pack2_bf16(y1.x, y1.y);
        a.u[3] = pack2_bf16(y1.z, y1.w);
        short8 b = *(const short8*)(Ws + (((kt * 4 + ct) * 4 + quad) * 16 + l16) * 8);
        acc = __builtin_amdgcn_mfma_f32_16x16x32_bf16(a.s, b, acc, 0, 0, 0);
    }

    const int base_row = rt * 16 + quad * 4;
#pragma unroll
    for (int r = 0; r < 4; ++r) {
        float v = acc[r];
        if (mat) v = softplusf(v) + 1e-3f;
        outp[(size_t)(base_row + r) * XD + col] = v;
    }
}

// ---------------- Kernel 2: fused responsibilities + sampling + losses 2/3/4/5 ----------------
// one wave per n
__global__ __launch_bounds__(256, 3) void fused_sample_kernel(
    const float* __restrict__ enc_mu_g, const float* __restrict__ enc_sig_g,
    const float* __restrict__ phi_mus, const float* __restrict__ phi_sigs,
    const float* __restrict__ phi_logits, const float4* __restrict__ tab4,
    const float* __restrict__ theta_logits, const float* __restrict__ lsetp,
    const float* __restrict__ u_noise, const float* __restrict__ eps_noise,
    const float* __restrict__ temperature,
    unsigned short* __restrict__ x_bf16, double* __restrict__ slots)
{
    __shared__ float red234[4], red5[4];
    const int wv = threadIdx.x >> 6;
    const int n = blockIdx.x * 4 + wv;
    const int d = threadIdx.x & 63;
    const int kd = d & 15;
    const int g = d >> 4;

    // ---- responsibilities: lane = (g, kd); partial over dims g*16..g*16+15 ----
    const float4* em4 = (const float4*)(enc_mu_g + (size_t)n * XD + g * 16);
    const float4* es4 = (const float4*)(enc_sig_g + (size_t)n * XD + g * 16);
    const float4* pm4 = (const float4*)(phi_mus + kd * XD + g * 16);
    const float4* ps4 = (const float4*)(phi_sigs + kd * XD + g * 16);

    float part = 0.f;
#pragma unroll
    for (int q = 0; q < 4; ++q) {
        float4 emv = em4[q], esv = es4[q], pmv = pm4[q], psv = ps4[q];
        {
            float sd = esv.x + psv.x; float df = (emv.x - pmv.x) * fast_rcp(sd);
            part += fmaf(-0.5f * df, df, -__logf(sd));
        }
        {
            float sd = esv.y + psv.y; float df = (emv.y - pmv.y) * fast_rcp(sd);
            part += fmaf(-0.5f * df, df, -__logf(sd));
        }
        {
            float sd = esv.z + psv.z; float df = (emv.z - pmv.z) * fast_rcp(sd);
            part += fmaf(-0.5f * df, df, -__logf(sd));
        }
        {
            float sd = esv.w + psv.w; float df = (emv.w - pmv.w) * fast_rcp(sd);
            part += fmaf(-0.5f * df, df, -__logf(sd));
        }
    }
    part += __shfl_xor(part, 16, 64);
    part += __shfl_xor(part, 32, 64);
    float zl = part + phi_logits[kd];

    // log_softmax over k (lane-parallel within 16-groups; zl now 4x replicated)
    float m = zl;
#pragma unroll
    for (int off = 1; off <= 8; off <<= 1) m = fmaxf(m, __shfl_xor(m, off, 64));
    float e0 = __expf(zl - m);
    float s0 = e0;
#pragma unroll
    for (int off = 1; off <= 8; off <<= 1) s0 += __shfl_xor(s0, off, 64);
    zl -= m + __logf(s0);

    // loss5 term
    float m3 = zl;
#pragma unroll
    for (int off = 1; off <= 8; off <<= 1) m3 = fmaxf(m3, __shfl_xor(m3, off, 64));
    float e3 = __expf(zl - m3);
    float s3 = e3;
#pragma unroll
    for (int off = 1; off <= 8; off <<= 1) s3 += __shfl_xor(s3, off, 64);
    float l5 = m3 + __logf(s3);

    // ---- sampling part ----
    const float invT = fast_rcp(temperature[0]);
    const float zl_l = zl;
    const float tl_l = theta_logits[kd];
    const float lset = lsetp[0];

    const float em = enc_mu_g[(size_t)n * XD + d];
    const float es = enc_sig_g[(size_t)n * XD + d];
    const float inv_es = fast_rcp(es);
    const float log_es = __logf(es);
    const float em_ie = inv_es * em;

    float mu[KK], Sg[KK], tm[KK], ts[KK], pm[KK], ps[KK];
#pragma unroll
    for (int k = 0; k < KK; ++k) {
        float4 tb = tab4[k * XD + d];     // {phi_mu, phi_sig, th_mu, th_sig}
        pm[k] = tb.x; ps[k] = tb.y; tm[k] = tb.z; ts[k] = tb.w;
        float ig = fast_rcp(tb.y);
        Sg[k] = fast_rcp(inv_es + ig);
        mu[k] = Sg[k] * fmaf(ig, tb.x, em_ie);
    }

    float eP[3], dzP[3], dthP[3];
#pragma unroll
    for (int p = 0; p < 3; ++p) {
        int sp = p * 4 + g;
        int spc = sp < SS ? sp : 0;       // clamp (results unused)
        float u = u_noise[((size_t)n * SS + spc) * KK + kd];
        float lg = (zl_l - __logf(-__logf(u))) * invT;
        float mg = lg;
        mg = fmaxf(mg, __shfl_xor(mg, 1, 64));
        mg = fmaxf(mg, __shfl_xor(mg, 2, 64));
        mg = fmaxf(mg, __shfl_xor(mg, 4, 64));
        mg = fmaxf(mg, __shfl_xor(mg, 8, 64));
        float e = __expf(lg - mg);
        float zs = e;
        zs += __shfl_xor(zs, 1, 64);
        zs += __shfl_xor(zs, 2, 64);
        zs += __shfl_xor(zs, 4, 64);
        zs += __shfl_xor(zs, 8, 64);
        e *= fast_rcp(zs);                 // normalized weight
        float pz = e * zl_l, pt = e * tl_l;
#pragma unroll
        for (int off = 1; off <= 8; off <<= 1) {
            pz += __shfl_xor(pz, off, 64);
            pt += __shfl_xor(pt, off, 64);
        }
        eP[p] = e; dzP[p] = pz; dthP[p] = pt;
    }

    float r_acc = 0.f, sc_acc = 0.f;
    const float* erow = eps_noise + (size_t)n * SS * XD + d;
    unsigned short* xrow = x_bf16 + (size_t)n * SS * XD + d;

#pragma unroll
    for (int s = 0; s < SS; ++s) {
        const int p = s >> 2, L = (s & 3) * 16;
        float ms = 0.f, Ssum = 0.f, tmu = 0.f, tsig = 0.f, pmu = 0.f, psig = 0.f;
#pragma unroll
        for (int k = 0; k < KK; ++k) {
            float ek = bcast(eP[p], L + k);
            ms   = fmaf(ek, mu[k], ms);
            Ssum = fmaf(ek, Sg[k], Ssum);
            tmu  = fmaf(ek, tm[k], tmu);
            tsig = fmaf(ek, ts[k], tsig);
            pmu  = fmaf(ek, pm[k], pmu);
            psig = fmaf(ek, ps[k], psig);
        }
        float ep = erow[s * XD];
        float x = fmaf(__builtin_amdgcn_sqrtf(Ssum), ep, ms);
        xrow[s * XD] = f32_to_bf16(x);

        float de  = (x - em) * inv_es;
        float rts = fast_rcp(tsig);
        float dt2 = (x - tmu) * rts;
        float dp  = (x - pmu) * fast_rcp(psig);
        r_acc += 0.5f * (de * de - dt2 * dt2 + dp * dp) + __logf(psig * rts);
        sc_acc += bcast(dthP[p], L) - bcast(dzP[p], L);
    }

    r_acc = fmaf((float)SS, log_es, r_acc);
    r_acc = wave_sum(r_acc);

    const float C234 = 0.5f * XD * 1.8378770664093453f;
    float total = r_acc + sc_acc + (float)SS * (C234 - lset);

    if (d == 0) { red234[wv] = total; red5[wv] = l5; }
    __syncthreads();
    if (threadIdx.x == 0) {
        atomicAdd(slots + (blockIdx.x & 63),
                  (double)(red234[0] + red234[1] + red234[2] + red234[3]));
        atomicAdd(slots + 64 + (blockIdx.x & 63),
                  (double)(red5[0] + red5[1] + red5[2] + red5[3]));
    }
}

// ---------------- Kernel 3: decoder via bf16 MFMA + fused loss1 ----------------
// grid dim3(NS/64, YD/64); block 256 = 4 waves; wave tile 16 rows x 64 cols
// 32 AGPR acc + ~50 VGPR -> 6 waves/SIMD for latency hiding of the
// exp/log/rcp epilogue chain.
__global__ __launch_bounds__(256, 6) void decoder_mfma(
    const unsigned short* __restrict__ xb,
    const unsigned short* __restrict__ wmu_s,
    const unsigned short* __restrict__ wsg_s,
    const float* __restrict__ bd_mu, const float* __restrict__ bd_sig,
    const float* __restrict__ Y, double* __restrict__ slots1,
    unsigned int magicS)
{
    __shared__ float red[4];
    const int t = threadIdx.x;
    const int w = t >> 6;
    const int lane = t & 63;
    const int l16 = lane & 15;
    const int quad = lane >> 4;
    const int mb = blockIdx.x;
    const int nb = blockIdx.y;

    const int row0 = mb * 64 + w * 16;

    const unsigned short* xp = xb + (size_t)(row0 + l16) * XD + quad * 8;
    const short8 a0 = *(const short8*)xp;
    const short8 a1 = *(const short8*)(xp + 32);

    f32x4 accmu[4], accsg[4];
#pragma unroll
    for (int tt = 0; tt < 4; ++tt) {
        int col = nb * 64 + tt * 16 + l16;
        float bm = bd_mu[col], bs = bd_sig[col];
        accmu[tt] = (f32x4){bm, bm, bm, bm};
        accsg[tt] = (f32x4){bs, bs, bs, bs};
    }

#pragma unroll
    for (int tt = 0; tt < 4; ++tt) {
        int tg = nb * 4 + tt;
        int boff = ((tg * 8 + quad) * 16 + l16) * 8;
        short8 b0 = *(const short8*)(wmu_s + boff);
        short8 b1 = *(const short8*)(wmu_s + boff + 512);
        short8 c0 = *(const short8*)(wsg_s + boff);
        short8 c1 = *(const short8*)(wsg_s + boff + 512);
        accmu[tt] = __builtin_amdgcn_mfma_f32_16x16x32_bf16(a0, b0, accmu[tt], 0, 0, 0);
        accmu[tt] = __builtin_amdgcn_mfma_f32_16x16x32_bf16(a1, b1, accmu[tt], 0, 0, 0);
        accsg[tt] = __builtin_amdgcn_mfma_f32_16x16x32_bf16(a0, c0, accsg[tt], 0, 0, 0);
        accsg[tt] = __builtin_amdgcn_mfma_f32_16x16x32_bf16(a1, c1, accsg[tt], 0, 0, 0);
    }

    float part = 0.f;
    const int m_base = row0 + quad * 4;
    float prod = 1.0f;
#pragma unroll
    for (int r = 0; r < 4; ++r) {
        int row = m_base + r;
        unsigned int ny = (unsigned int)(((unsigned long long)(unsigned int)row * magicS) >> 35);
        const float* Yr = Y + (size_t)ny * YD + nb * 64 + l16;
#pragma unroll
        for (int tt = 0; tt < 4; ++tt) {
            float Yv = Yr[tt * 16];
            // |acc_sig| <= ~6 (sigma ~0.6): direct softplus is safe, no max-form
            float sig = __logf(1.0f + __expf(accsg[tt][r])) + 1e-3f;
            float diff = (Yv - accmu[tt][r]) * fast_rcp(sig);
            part = fmaf(-0.5f * diff, diff, part);
            prod *= sig;
        }
        if (r & 1) {                      // batch log over 8 sigmas (>=1e-24)
            part -= __logf(prod);
            prod = 1.0f;
        }
    }
    part = wave_sum(part);
    if (lane == 0) red[w] = part;
    __syncthreads();
    if (t == 0) {
        atomicAdd(slots1 + ((blockIdx.y * gridDim.x + blockIdx.x) & 63),
                  (double)(red[0] + red[1] + red[2] + red[3]));
    }
}

// ---------------- Kernel 4: finalize ----------------
__global__ void finalize_kernel(const double* __restrict__ slots,
                                float* __restrict__ out, int NS, int S)
{
    double l234 = 0.0, l5 = 0.0, l1 = 0.0;
    for (int i = 0; i < 64; ++i) {
        l234 += slots[i];
        l5   += slots[64 + i];
        l1   += slots[128 + i];
    }
    l1 += (double)NS * (-0.5 * (double)YD * 1.8378770664093453);
    out[0] = (float)(-((l1 + l234) / (double)S + l5));
}

extern "C" void kernel_launch(void* const* d_in, const int* in_sizes, int n_in,
                              void* d_out, int out_size, void* d_ws, size_t ws_size,
                              hipStream_t stream) {
    const float* Y            = (const float*)d_in[0];
    const float* We_mu        = (const float*)d_in[1];
    const float* be_mu        = (const float*)d_in[2];
    const float* We_sig       = (const float*)d_in[3];
    const float* be_sig       = (const float*)d_in[4];
    const float* Wd_mu        = (const float*)d_in[5];
    const float* bd_mu        = (const float*)d_in[6];
    const float* Wd_sig       = (const float*)d_in[7];
    const float* bd_sig       = (const float*)d_in[8];
    const float* phi_mus      = (const float*)d_in[9];
    const float* phi_sigs     = (const float*)d_in[10];
    const float* phi_logits   = (const float*)d_in[11];
    const float* theta_mus    = (const float*)d_in[12];
    const float* theta_sigs   = (const float*)d_in[13];
    const float* theta_logits = (const float*)d_in[14];
    const float* u_noise      = (const float*)d_in[15];
    const float* eps_noise    = (const float*)d_in[16];
    const float* temperature  = (const float*)d_in[17];

    const int N = in_sizes[0] / YD;           // 8192
    const int S = in_sizes[15] / (N * KK);    // 10 (== SS)
    const int NS = N * S;
    const unsigned int magicS =
        (unsigned int)((((unsigned long long)1 << 35) + S - 1) / (unsigned long long)S);

    char* base = (char*)d_ws;
    double* slots = (double*)base;                       // 192 doubles (3 x 64)
    float* enc_mu  = (float*)(base + 2048);
    float* enc_sig = enc_mu + (size_t)N * XD;
    float* zlp     = enc_sig + (size_t)N * XD;           // (unused, layout kept)
    float4* tab4   = (float4*)(zlp + (size_t)N * KK);    // 1024 float4
    float* lsetp   = (float*)(tab4 + 1024);
    unsigned short* xb    = (unsigned short*)(lsetp + 16);
    unsigned short* wmu_s = xb + (size_t)NS * XD;
    unsigned short* wsg_s = wmu_s + 32768;
    unsigned short* wenc  = wsg_s + 32768;               // 2 x 32768

    hipMemsetAsync(slots, 0, 2048, stream);

    prep_kernel<<<517, 256, 0, stream>>>(Wd_mu, Wd_sig, We_mu, We_sig,
                                         phi_mus, phi_sigs, theta_mus,
                                         theta_sigs, theta_logits,
                                         wmu_s, wsg_s, wenc, tab4, lsetp);
    encoder_mfma<<<(N / 16) * 2, 256, 0, stream>>>(Y, wenc, be_mu, be_sig,
                                                   enc_mu, enc_sig);
    fused_sample_kernel<<<N / 4, 256, 0, stream>>>(enc_mu, enc_sig,
                                                   phi_mus, phi_sigs, phi_logits,
                                                   tab4, theta_logits, lsetp,
                                                   u_noise, eps_noise, temperature,
                                                   xb, slots);
    decoder_mfma<<<dim3(NS / 64, YD / 64), 256, 0, stream>>>(
        xb, wmu_s, wsg_s, bd_mu, bd_sig, Y, slots + 128, magicS);
    finalize_kernel<<<1, 1, 0, stream>>>(slots, (float*)d_out, NS, S);
}

// Round 8
// 203.128 us; speedup vs baseline: 1.0532x; 1.0532x over previous
//
#include <hip/hip_runtime.h>
#include <math.h>

#define YD 512
#define XD 64
#define KK 16
#define SS 10

typedef __attribute__((ext_vector_type(8))) short short8;
typedef __attribute__((ext_vector_type(4))) float f32x4;

__device__ __forceinline__ float wave_sum(float v) {
#pragma unroll
    for (int off = 32; off > 0; off >>= 1) v += __shfl_xor(v, off, 64);
    return v;
}

__device__ __forceinline__ float fast_rcp(float x) {
    return __builtin_amdgcn_rcpf(x);
}

__device__ __forceinline__ float bcast(float v, int l) {
    return __uint_as_float((unsigned int)__builtin_amdgcn_readlane((int)__float_as_uint(v), l));
}

__device__ __forceinline__ float softplusf(float x) {
    return fmaxf(x, 0.0f) + __logf(1.0f + __expf(-fabsf(x)));
}

__device__ __forceinline__ unsigned short f32_to_bf16(float f) {
    union { float f; unsigned int u; } v; v.f = f;
    unsigned int r = v.u + 0x7fffu + ((v.u >> 16) & 1u);
    return (unsigned short)(r >> 16);
}

__device__ __forceinline__ unsigned int pack2_bf16(float a, float b) {
    unsigned int ua = __float_as_uint(a), ub = __float_as_uint(b);
    ua = (ua + 0x7fffu + ((ua >> 16) & 1u)) >> 16;
    ub = (ub + 0x7fffu + ((ub >> 16) & 1u)) & 0xffff0000u;
    return ua | ub;
}

// ---------------- Kernel 0: prep ----------------
__global__ __launch_bounds__(256) void prep_kernel(
    const float* __restrict__ Wd_mu, const float* __restrict__ Wd_sig,
    const float* __restrict__ We_mu, const float* __restrict__ We_sig,
    const float* __restrict__ phi_mus, const float* __restrict__ phi_sigs,
    const float* __restrict__ theta_mus, const float* __restrict__ theta_sigs,
    const float* __restrict__ theta_logits,
    unsigned short* __restrict__ wmu_s, unsigned short* __restrict__ wsg_s,
    unsigned short* __restrict__ wenc,
    float4* __restrict__ tab4, float* __restrict__ lsetp)
{
    int idx = blockIdx.x * 256 + threadIdx.x;
    if (idx < 65536) {
        int mat = idx >> 15;            // 0: mu, 1: sig
        int e = idx & 32767;
        int j = e & 7;
        int n = (e >> 3) & 15;
        int q = (e >> 7) & 7;
        int tg = e >> 10;
        int k = q * 8 + j;
        int col = tg * 16 + n;
        const float* W = mat ? Wd_sig : Wd_mu;
        unsigned short* o = mat ? wsg_s : wmu_s;
        o[e] = f32_to_bf16(W[k * YD + col]);
    } else if (idx < 131072) {
        int ii = idx - 65536;
        int mat = ii >> 15;             // 0: We_mu, 1: We_sig
        int e = ii & 32767;
        int j = e & 7;
        int n = (e >> 3) & 15;
        int q = (e >> 7) & 3;
        int ct = (e >> 9) & 3;
        int kt = e >> 11;
        int k = kt * 32 + q * 8 + j;    // 0..511
        int col = ct * 16 + n;          // 0..63
        const float* W = mat ? We_sig : We_mu;
        wenc[mat * 32768 + e] = f32_to_bf16(W[k * XD + col]);
    } else if (idx < 131072 + 1024) {
        int e = idx - 131072;
        float4 t;
        t.x = phi_mus[e];
        t.y = phi_sigs[e];
        t.z = theta_mus[e];
        t.w = theta_sigs[e];
        tab4[e] = t;
    } else if (idx == 131072 + 1024) {
        float mt = theta_logits[0];
        for (int k = 1; k < KK; ++k) mt = fmaxf(mt, theta_logits[k]);
        float st = 0.f;
        for (int k = 0; k < KK; ++k) st += __expf(theta_logits[k] - mt);
        lsetp[0] = mt + __logf(st);
    }
}

// ---------------- Kernel 1: encoder via bf16 MFMA ----------------
__global__ __launch_bounds__(256) void encoder_mfma(
    const float* __restrict__ Y,
    const unsigned short* __restrict__ wenc,  // [2][32768] swizzled bf16
    const float* __restrict__ be_mu, const float* __restrict__ be_sig,
    float* __restrict__ enc_mu, float* __restrict__ enc_sig)
{
    const int t = threadIdx.x;
    const int w = t >> 6, lane = t & 63, l16 = lane & 15, quad = lane >> 4;
    const int mat = blockIdx.x & 1;
    const int rt = blockIdx.x >> 1;            // 16-row tile
    const int row = rt * 16 + l16;
    const int ct = w;                          // col tile 0..3
    const unsigned short* Ws = wenc + mat * 32768;
    const float4* Yrow = (const float4*)(Y + (size_t)row * YD);

    const float* bias = mat ? be_sig : be_mu;
    float* outp = mat ? enc_sig : enc_mu;
    const int col = ct * 16 + l16;
    const float bv = bias[col];
    f32x4 acc = (f32x4){bv, bv, bv, bv};

#pragma unroll
    for (int kt = 0; kt < 16; ++kt) {
        float4 y0 = Yrow[kt * 8 + quad * 2];
        float4 y1 = Yrow[kt * 8 + quad * 2 + 1];
        union { short8 s; unsigned int u[4]; } a;
        a.u[0] = pack2_bf16(y0.x, y0.y);
        a.u[1] = pack2_bf16(y0.z, y0.w);
        a.u[2] = pack2_bf16(y1.x, y1.y);
        a.u[3] = pack2_bf16(y1.z, y1.w);
        short8 b = *(const short8*)(Ws + (((kt * 4 + ct) * 4 + quad) * 16 + l16) * 8);
        acc = __builtin_amdgcn_mfma_f32_16x16x32_bf16(a.s, b, acc, 0, 0, 0);
    }

    const int base_row = rt * 16 + quad * 4;
#pragma unroll
    for (int r = 0; r < 4; ++r) {
        float v = acc[r];
        if (mat) v = softplusf(v) + 1e-3f;
        outp[(size_t)(base_row + r) * XD + col] = v;
    }
}

// ---------------- Kernel 2: fused responsibilities + sampling + losses 2/3/4/5 ----------------
// one wave per n
__global__ __launch_bounds__(256, 3) void fused_sample_kernel(
    const float* __restrict__ enc_mu_g, const float* __restrict__ enc_sig_g,
    const float* __restrict__ phi_mus, const float* __restrict__ phi_sigs,
    const float* __restrict__ phi_logits, const float4* __restrict__ tab4,
    const float* __restrict__ theta_logits, const float* __restrict__ lsetp,
    const float* __restrict__ u_noise, const float* __restrict__ eps_noise,
    const float* __restrict__ temperature,
    unsigned short* __restrict__ x_bf16, double* __restrict__ slots)
{
    __shared__ float red234[4], red5[4];
    const int wv = threadIdx.x >> 6;
    const int n = blockIdx.x * 4 + wv;
    const int d = threadIdx.x & 63;
    const int kd = d & 15;
    const int g = d >> 4;

    // ---- responsibilities: lane = (g, kd); partial over dims g*16..g*16+15 ----
    const float4* em4 = (const float4*)(enc_mu_g + (size_t)n * XD + g * 16);
    const float4* es4 = (const float4*)(enc_sig_g + (size_t)n * XD + g * 16);
    const float4* pm4 = (const float4*)(phi_mus + kd * XD + g * 16);
    const float4* ps4 = (const float4*)(phi_sigs + kd * XD + g * 16);

    float part = 0.f;
#pragma unroll
    for (int q = 0; q < 4; ++q) {
        float4 emv = em4[q], esv = es4[q], pmv = pm4[q], psv = ps4[q];
        {
            float sd = esv.x + psv.x; float df = (emv.x - pmv.x) * fast_rcp(sd);
            part += fmaf(-0.5f * df, df, -__logf(sd));
        }
        {
            float sd = esv.y + psv.y; float df = (emv.y - pmv.y) * fast_rcp(sd);
            part += fmaf(-0.5f * df, df, -__logf(sd));
        }
        {
            float sd = esv.z + psv.z; float df = (emv.z - pmv.z) * fast_rcp(sd);
            part += fmaf(-0.5f * df, df, -__logf(sd));
        }
        {
            float sd = esv.w + psv.w; float df = (emv.w - pmv.w) * fast_rcp(sd);
            part += fmaf(-0.5f * df, df, -__logf(sd));
        }
    }
    part += __shfl_xor(part, 16, 64);
    part += __shfl_xor(part, 32, 64);
    float zl = part + phi_logits[kd];

    // log_softmax over k (lane-parallel within 16-groups; zl now 4x replicated)
    float m = zl;
#pragma unroll
    for (int off = 1; off <= 8; off <<= 1) m = fmaxf(m, __shfl_xor(m, off, 64));
    float e0 = __expf(zl - m);
    float s0 = e0;
#pragma unroll
    for (int off = 1; off <= 8; off <<= 1) s0 += __shfl_xor(s0, off, 64);
    zl -= m + __logf(s0);

    // loss5 term
    float m3 = zl;
#pragma unroll
    for (int off = 1; off <= 8; off <<= 1) m3 = fmaxf(m3, __shfl_xor(m3, off, 64));
    float e3 = __expf(zl - m3);
    float s3 = e3;
#pragma unroll
    for (int off = 1; off <= 8; off <<= 1) s3 += __shfl_xor(s3, off, 64);
    float l5 = m3 + __logf(s3);

    // ---- sampling part ----
    const float invT = fast_rcp(temperature[0]);
    const float zl_l = zl;
    const float tl_l = theta_logits[kd];
    const float lset = lsetp[0];

    const float em = enc_mu_g[(size_t)n * XD + d];
    const float es = enc_sig_g[(size_t)n * XD + d];
    const float inv_es = fast_rcp(es);
    const float log_es = __logf(es);
    const float em_ie = inv_es * em;

    float mu[KK], Sg[KK], tm[KK], ts[KK], pm[KK], ps[KK];
#pragma unroll
    for (int k = 0; k < KK; ++k) {
        float4 tb = tab4[k * XD + d];     // {phi_mu, phi_sig, th_mu, th_sig}
        pm[k] = tb.x; ps[k] = tb.y; tm[k] = tb.z; ts[k] = tb.w;
        float ig = fast_rcp(tb.y);
        Sg[k] = fast_rcp(inv_es + ig);
        mu[k] = Sg[k] * fmaf(ig, tb.x, em_ie);
    }

    // gumbel: 4 samples per pass; lane = (sgrp = g, k = kd)
    // dz/dth scalar sums are deferred: esc = sum over (s,k) lanes of
    // e*(tl - zl), folded into the single final wave_sum.
    float eP[3];
    float esc = 0.f;
#pragma unroll
    for (int p = 0; p < 3; ++p) {
        int sp = p * 4 + g;
        int spc = sp < SS ? sp : 0;       // clamp (masked below)
        float u = u_noise[((size_t)n * SS + spc) * KK + kd];
        float lg = (zl_l - __logf(-__logf(u))) * invT;
        float mg = lg;
        mg = fmaxf(mg, __shfl_xor(mg, 1, 64));
        mg = fmaxf(mg, __shfl_xor(mg, 2, 64));
        mg = fmaxf(mg, __shfl_xor(mg, 4, 64));
        mg = fmaxf(mg, __shfl_xor(mg, 8, 64));
        float e = __expf(lg - mg);
        float zs = e;
        zs += __shfl_xor(zs, 1, 64);
        zs += __shfl_xor(zs, 2, 64);
        zs += __shfl_xor(zs, 4, 64);
        zs += __shfl_xor(zs, 8, 64);
        e *= fast_rcp(zs);                 // normalized weight
        eP[p] = e;
        if (sp < SS) esc = fmaf(e, tl_l - zl_l, esc);
    }

    float r_acc = 0.f;
    const float* erow = eps_noise + (size_t)n * SS * XD + d;
    unsigned short* xrow = x_bf16 + (size_t)n * SS * XD + d;

#pragma unroll
    for (int s = 0; s < SS; ++s) {
        const int p = s >> 2, L = (s & 3) * 16;
        float ms = 0.f, Ssum = 0.f, tmu = 0.f, tsig = 0.f, pmu = 0.f, psig = 0.f;
#pragma unroll
        for (int k = 0; k < KK; ++k) {
            float ek = bcast(eP[p], L + k);
            ms   = fmaf(ek, mu[k], ms);
            Ssum = fmaf(ek, Sg[k], Ssum);
            tmu  = fmaf(ek, tm[k], tmu);
            tsig = fmaf(ek, ts[k], tsig);
            pmu  = fmaf(ek, pm[k], pmu);
            psig = fmaf(ek, ps[k], psig);
        }
        float ep = erow[s * XD];
        float x = fmaf(__builtin_amdgcn_sqrtf(Ssum), ep, ms);
        xrow[s * XD] = f32_to_bf16(x);

        float de  = (x - em) * inv_es;
        float rts = fast_rcp(tsig);
        float dt2 = (x - tmu) * rts;
        float dp  = (x - pmu) * fast_rcp(psig);
        r_acc += 0.5f * (de * de - dt2 * dt2 + dp * dp) + __logf(psig * rts);
    }

    r_acc = fmaf((float)SS, log_es, r_acc);
    r_acc += esc;
    r_acc = wave_sum(r_acc);

    const float C234 = 0.5f * XD * 1.8378770664093453f;
    float total = r_acc + (float)SS * (C234 - lset);

    if (d == 0) { red234[wv] = total; red5[wv] = l5; }
    __syncthreads();
    if (threadIdx.x == 0) {
        atomicAdd(slots + (blockIdx.x & 63),
                  (double)(red234[0] + red234[1] + red234[2] + red234[3]));
        atomicAdd(slots + 64 + (blockIdx.x & 63),
                  (double)(red5[0] + red5[1] + red5[2] + red5[3]));
    }
}

// ---------------- Kernel 3: decoder via bf16 MFMA + fused loss1 ----------------
// grid dim3(NS/128, YD/64); block 256 = 4 waves; wave tile 32 rows x 64 cols
// (r6 shape — per-wave overhead amortization beat occupancy in r6 vs r7 A/B).
// Y loads hoisted ahead of the transcendental chain; one magic-div per
// row-group with compare-increment for the remaining rows.
__global__ __launch_bounds__(256) void decoder_mfma(
    const unsigned short* __restrict__ xb,
    const unsigned short* __restrict__ wmu_s,
    const unsigned short* __restrict__ wsg_s,
    const float* __restrict__ bd_mu, const float* __restrict__ bd_sig,
    const float* __restrict__ Y, double* __restrict__ slots1,
    unsigned int magicS)
{
    __shared__ float red[4];
    const int t = threadIdx.x;
    const int w = t >> 6;
    const int lane = t & 63;
    const int l16 = lane & 15;
    const int quad = lane >> 4;
    const int mb = blockIdx.x;
    const int nb = blockIdx.y;

    const int row0 = mb * 128 + w * 32;

    short8 a[2][2];
#pragma unroll
    for (int rg = 0; rg < 2; ++rg) {
        const unsigned short* xp = xb + (size_t)(row0 + rg * 16 + l16) * XD + quad * 8;
        a[rg][0] = *(const short8*)xp;
        a[rg][1] = *(const short8*)(xp + 32);
    }

    f32x4 accmu[2][4], accsg[2][4];
#pragma unroll
    for (int tt = 0; tt < 4; ++tt) {
        int col = nb * 64 + tt * 16 + l16;
        float bm = bd_mu[col], bs = bd_sig[col];
#pragma unroll
        for (int rg = 0; rg < 2; ++rg) {
            accmu[rg][tt] = (f32x4){bm, bm, bm, bm};
            accsg[rg][tt] = (f32x4){bs, bs, bs, bs};
        }
    }

#pragma unroll
    for (int tt = 0; tt < 4; ++tt) {
        int tg = nb * 4 + tt;
        int boff = ((tg * 8 + quad) * 16 + l16) * 8;
        short8 b0 = *(const short8*)(wmu_s + boff);
        short8 b1 = *(const short8*)(wmu_s + boff + 512);
        short8 c0 = *(const short8*)(wsg_s + boff);
        short8 c1 = *(const short8*)(wsg_s + boff + 512);
#pragma unroll
        for (int rg = 0; rg < 2; ++rg) {
            accmu[rg][tt] = __builtin_amdgcn_mfma_f32_16x16x32_bf16(a[rg][0], b0, accmu[rg][tt], 0, 0, 0);
            accmu[rg][tt] = __builtin_amdgcn_mfma_f32_16x16x32_bf16(a[rg][1], b1, accmu[rg][tt], 0, 0, 0);
            accsg[rg][tt] = __builtin_amdgcn_mfma_f32_16x16x32_bf16(a[rg][0], c0, accsg[rg][tt], 0, 0, 0);
            accsg[rg][tt] = __builtin_amdgcn_mfma_f32_16x16x32_bf16(a[rg][1], c1, accsg[rg][tt], 0, 0, 0);
        }
    }

    float part = 0.f;
#pragma unroll
    for (int rg = 0; rg < 2; ++rg) {
        const int m_base = row0 + rg * 16 + quad * 4;
        unsigned int q10 = (unsigned int)(((unsigned long long)(unsigned int)m_base * magicS) >> 35);
        int rem = m_base - (int)q10 * 10;     // 0..9

        // hoist all 16 Y loads of this row-group (32-bit saddr indexing)
        float Yv[4][4];
#pragma unroll
        for (int r = 0; r < 4; ++r) {
            unsigned int ny = q10 + ((rem + r) >= 10 ? 1u : 0u);
            unsigned int iy = ny * YD + nb * 64 + l16;
#pragma unroll
            for (int tt = 0; tt < 4; ++tt) Yv[r][tt] = Y[iy + tt * 16];
        }

        float prod = 1.0f;
#pragma unroll
        for (int r = 0; r < 4; ++r) {
#pragma unroll
            for (int tt = 0; tt < 4; ++tt) {
                // |acc_sig| small (sigma ~0.6): direct softplus, no max-form
                float sig = __logf(1.0f + __expf(accsg[rg][tt][r])) + 1e-3f;
                float diff = (Yv[r][tt] - accmu[rg][tt][r]) * fast_rcp(sig);
                part = fmaf(-0.5f * diff, diff, part);
                prod *= sig;
            }
            if (r & 1) {                  // batch log over 8 sigmas (>=1e-24)
                part -= __logf(prod);
                prod = 1.0f;
            }
        }
    }
    part = wave_sum(part);
    if (lane == 0) red[w] = part;
    __syncthreads();
    if (t == 0) {
        atomicAdd(slots1 + ((blockIdx.y * gridDim.x + blockIdx.x) & 63),
                  (double)(red[0] + red[1] + red[2] + red[3]));
    }
}

// ---------------- Kernel 4: finalize ----------------
__global__ void finalize_kernel(const double* __restrict__ slots,
                                float* __restrict__ out, int NS, int S)
{
    double l234 = 0.0, l5 = 0.0, l1 = 0.0;
    for (int i = 0; i < 64; ++i) {
        l234 += slots[i];
        l5   += slots[64 + i];
        l1   += slots[128 + i];
    }
    l1 += (double)NS * (-0.5 * (double)YD * 1.8378770664093453);
    out[0] = (float)(-((l1 + l234) / (double)S + l5));
}

extern "C" void kernel_launch(void* const* d_in, const int* in_sizes, int n_in,
                              void* d_out, int out_size, void* d_ws, size_t ws_size,
                              hipStream_t stream) {
    const float* Y            = (const float*)d_in[0];
    const float* We_mu        = (const float*)d_in[1];
    const float* be_mu        = (const float*)d_in[2];
    const float* We_sig       = (const float*)d_in[3];
    const float* be_sig       = (const float*)d_in[4];
    const float* Wd_mu        = (const float*)d_in[5];
    const float* bd_mu        = (const float*)d_in[6];
    const float* Wd_sig       = (const float*)d_in[7];
    const float* bd_sig       = (const float*)d_in[8];
    const float* phi_mus      = (const float*)d_in[9];
    const float* phi_sigs     = (const float*)d_in[10];
    const float* phi_logits   = (const float*)d_in[11];
    const float* theta_mus    = (const float*)d_in[12];
    const float* theta_sigs   = (const float*)d_in[13];
    const float* theta_logits = (const float*)d_in[14];
    const float* u_noise      = (const float*)d_in[15];
    const float* eps_noise    = (const float*)d_in[16];
    const float* temperature  = (const float*)d_in[17];

    const int N = in_sizes[0] / YD;           // 8192
    const int S = in_sizes[15] / (N * KK);    // 10 (== SS)
    const int NS = N * S;
    const unsigned int magicS =
        (unsigned int)((((unsigned long long)1 << 35) + S - 1) / (unsigned long long)S);

    char* base = (char*)d_ws;
    double* slots = (double*)base;                       // 192 doubles (3 x 64)
    float* enc_mu  = (float*)(base + 2048);
    float* enc_sig = enc_mu + (size_t)N * XD;
    float* zlp     = enc_sig + (size_t)N * XD;           // (unused, layout kept)
    float4* tab4   = (float4*)(zlp + (size_t)N * KK);    // 1024 float4
    float* lsetp   = (float*)(tab4 + 1024);
    unsigned short* xb    = (unsigned short*)(lsetp + 16);
    unsigned short* wmu_s = xb + (size_t)NS * XD;
    unsigned short* wsg_s = wmu_s + 32768;
    unsigned short* wenc  = wsg_s + 32768;               // 2 x 32768

    hipMemsetAsync(slots, 0, 2048, stream);

    prep_kernel<<<517, 256, 0, stream>>>(Wd_mu, Wd_sig, We_mu, We_sig,
                                         phi_mus, phi_sigs, theta_mus,
                                         theta_sigs, theta_logits,
                                         wmu_s, wsg_s, wenc, tab4, lsetp);
    encoder_mfma<<<(N / 16) * 2, 256, 0, stream>>>(Y, wenc, be_mu, be_sig,
                                                   enc_mu, enc_sig);
    fused_sample_kernel<<<N / 4, 256, 0, stream>>>(enc_mu, enc_sig,
                                                   phi_mus, phi_sigs, phi_logits,
                                                   tab4, theta_logits, lsetp,
                                                   u_noise, eps_noise, temperature,
                                                   xb, slots);
    decoder_mfma<<<dim3(NS / 128, YD / 64), 256, 0, stream>>>(
        xb, wmu_s, wsg_s, bd_mu, bd_sig, Y, slots + 128, magicS);
    finalize_kernel<<<1, 1, 0, stream>>>(slots, (float*)d_out, NS, S);
}

// Round 12
// 201.190 us; speedup vs baseline: 1.0634x; 1.0096x over previous
//
#include <hip/hip_runtime.h>
#include <math.h>

#define YD 512
#define XD 64
#define KK 16
#define SS 10

typedef __attribute__((ext_vector_type(8))) short short8;
typedef __attribute__((ext_vector_type(4))) float f32x4;

__device__ __forceinline__ float wave_sum(float v) {
#pragma unroll
    for (int off = 32; off > 0; off >>= 1) v += __shfl_xor(v, off, 64);
    return v;
}

__device__ __forceinline__ float fast_rcp(float x) {
    return __builtin_amdgcn_rcpf(x);
}

// base-2 HW transcendentals: v_exp_f32 computes 2^x, v_log_f32 computes log2(x)
__device__ __forceinline__ float hw_exp2(float x) {
    return __builtin_amdgcn_exp2f(x);
}
__device__ __forceinline__ float hw_log2(float x) {
    return __builtin_amdgcn_logf(x);
}

__device__ __forceinline__ float bcast(float v, int l) {
    return __uint_as_float((unsigned int)__builtin_amdgcn_readlane((int)__float_as_uint(v), l));
}

__device__ __forceinline__ float softplusf(float x) {
    return fmaxf(x, 0.0f) + __logf(1.0f + __expf(-fabsf(x)));
}

__device__ __forceinline__ unsigned short f32_to_bf16(float f) {
    union { float f; unsigned int u; } v; v.f = f;
    unsigned int r = v.u + 0x7fffu + ((v.u >> 16) & 1u);
    return (unsigned short)(r >> 16);
}

__device__ __forceinline__ unsigned int pack2_bf16(float a, float b) {
    unsigned int ua = __float_as_uint(a), ub = __float_as_uint(b);
    ua = (ua + 0x7fffu + ((ua >> 16) & 1u)) >> 16;
    ub = (ub + 0x7fffu + ((ub >> 16) & 1u)) & 0xffff0000u;
    return ua | ub;
}

// ---------------- Kernel 0: prep ----------------
__global__ __launch_bounds__(256) void prep_kernel(
    const float* __restrict__ Wd_mu, const float* __restrict__ Wd_sig,
    const float* __restrict__ We_mu, const float* __restrict__ We_sig,
    const float* __restrict__ phi_mus, const float* __restrict__ phi_sigs,
    const float* __restrict__ theta_mus, const float* __restrict__ theta_sigs,
    const float* __restrict__ theta_logits,
    unsigned short* __restrict__ wmu_s, unsigned short* __restrict__ wsg_s,
    unsigned short* __restrict__ wenc,
    float4* __restrict__ tab4, float* __restrict__ lsetp)
{
    int idx = blockIdx.x * 256 + threadIdx.x;
    if (idx < 65536) {
        int mat = idx >> 15;            // 0: mu, 1: sig
        int e = idx & 32767;
        int j = e & 7;
        int n = (e >> 3) & 15;
        int q = (e >> 7) & 7;
        int tg = e >> 10;
        int k = q * 8 + j;
        int col = tg * 16 + n;
        const float* W = mat ? Wd_sig : Wd_mu;
        unsigned short* o = mat ? wsg_s : wmu_s;
        o[e] = f32_to_bf16(W[k * YD + col]);
    } else if (idx < 131072) {
        int ii = idx - 65536;
        int mat = ii >> 15;             // 0: We_mu, 1: We_sig
        int e = ii & 32767;
        int j = e & 7;
        int n = (e >> 3) & 15;
        int q = (e >> 7) & 3;
        int ct = (e >> 9) & 3;
        int kt = e >> 11;
        int k = kt * 32 + q * 8 + j;    // 0..511
        int col = ct * 16 + n;          // 0..63
        const float* W = mat ? We_sig : We_mu;
        wenc[mat * 32768 + e] = f32_to_bf16(W[k * XD + col]);
    } else if (idx < 131072 + 1024) {
        int e = idx - 131072;
        float4 t;
        t.x = phi_mus[e];
        t.y = phi_sigs[e];
        t.z = theta_mus[e];
        t.w = theta_sigs[e];
        tab4[e] = t;
    } else if (idx == 131072 + 1024) {
        float mt = theta_logits[0];
        for (int k = 1; k < KK; ++k) mt = fmaxf(mt, theta_logits[k]);
        float st = 0.f;
        for (int k = 0; k < KK; ++k) st += __expf(theta_logits[k] - mt);
        lsetp[0] = mt + __logf(st);
    }
}

// ---------------- Kernel 1: encoder via bf16 MFMA ----------------
__global__ __launch_bounds__(256) void encoder_mfma(
    const float* __restrict__ Y,
    const unsigned short* __restrict__ wenc,  // [2][32768] swizzled bf16
    const float* __restrict__ be_mu, const float* __restrict__ be_sig,
    float* __restrict__ enc_mu, float* __restrict__ enc_sig)
{
    const int t = threadIdx.x;
    const int w = t >> 6, lane = t & 63, l16 = lane & 15, quad = lane >> 4;
    const int mat = blockIdx.x & 1;
    const int rt = blockIdx.x >> 1;            // 16-row tile
    const int row = rt * 16 + l16;
    const int ct = w;                          // col tile 0..3
    const unsigned short* Ws = wenc + mat * 32768;
    const float4* Yrow = (const float4*)(Y + (size_t)row * YD);

    const float* bias = mat ? be_sig : be_mu;
    float* outp = mat ? enc_sig : enc_mu;
    const int col = ct * 16 + l16;
    const float bv = bias[col];
    f32x4 acc = (f32x4){bv, bv, bv, bv};

#pragma unroll
    for (int kt = 0; kt < 16; ++kt) {
        float4 y0 = Yrow[kt * 8 + quad * 2];
        float4 y1 = Yrow[kt * 8 + quad * 2 + 1];
        union { short8 s; unsigned int u[4]; } a;
        a.u[0] = pack2_bf16(y0.x, y0.y);
        a.u[1] = pack2_bf16(y0.z, y0.w);
        a.u[2] = pack2_bf16(y1.x, y1.y);
        a.u[3] = pack2_bf16(y1.z, y1.w);
        short8 b = *(const short8*)(Ws + (((kt * 4 + ct) * 4 + quad) * 16 + l16) * 8);
        acc = __builtin_amdgcn_mfma_f32_16x16x32_bf16(a.s, b, acc, 0, 0, 0);
    }

    const int base_row = rt * 16 + quad * 4;
#pragma unroll
    for (int r = 0; r < 4; ++r) {
        float v = acc[r];
        if (mat) v = softplusf(v) + 1e-3f;
        outp[(size_t)(base_row + r) * XD + col] = v;
    }
}

// ---------------- Kernel 2: fused responsibilities + sampling + losses 2/3/4/5 ----------------
// one wave per n
__global__ __launch_bounds__(256, 3) void fused_sample_kernel(
    const float* __restrict__ enc_mu_g, const float* __restrict__ enc_sig_g,
    const float* __restrict__ phi_mus, const float* __restrict__ phi_sigs,
    const float* __restrict__ phi_logits, const float4* __restrict__ tab4,
    const float* __restrict__ theta_logits, const float* __restrict__ lsetp,
    const float* __restrict__ u_noise, const float* __restrict__ eps_noise,
    const float* __restrict__ temperature,
    unsigned short* __restrict__ x_bf16, double* __restrict__ slots)
{
    __shared__ float red234[4], red5[4];
    const int wv = threadIdx.x >> 6;
    const int n = blockIdx.x * 4 + wv;
    const int d = threadIdx.x & 63;
    const int kd = d & 15;
    const int g = d >> 4;

    // ---- responsibilities: lane = (g, kd); partial over dims g*16..g*16+15 ----
    const float4* em4 = (const float4*)(enc_mu_g + (size_t)n * XD + g * 16);
    const float4* es4 = (const float4*)(enc_sig_g + (size_t)n * XD + g * 16);
    const float4* pm4 = (const float4*)(phi_mus + kd * XD + g * 16);
    const float4* ps4 = (const float4*)(phi_sigs + kd * XD + g * 16);

    float part = 0.f;
#pragma unroll
    for (int q = 0; q < 4; ++q) {
        float4 emv = em4[q], esv = es4[q], pmv = pm4[q], psv = ps4[q];
        {
            float sd = esv.x + psv.x; float df = (emv.x - pmv.x) * fast_rcp(sd);
            part += fmaf(-0.5f * df, df, -__logf(sd));
        }
        {
            float sd = esv.y + psv.y; float df = (emv.y - pmv.y) * fast_rcp(sd);
            part += fmaf(-0.5f * df, df, -__logf(sd));
        }
        {
            float sd = esv.z + psv.z; float df = (emv.z - pmv.z) * fast_rcp(sd);
            part += fmaf(-0.5f * df, df, -__logf(sd));
        }
        {
            float sd = esv.w + psv.w; float df = (emv.w - pmv.w) * fast_rcp(sd);
            part += fmaf(-0.5f * df, df, -__logf(sd));
        }
    }
    part += __shfl_xor(part, 16, 64);
    part += __shfl_xor(part, 32, 64);
    float zl = part + phi_logits[kd];

    // log_softmax over k (lane-parallel within 16-groups; zl now 4x replicated)
    float m = zl;
#pragma unroll
    for (int off = 1; off <= 8; off <<= 1) m = fmaxf(m, __shfl_xor(m, off, 64));
    float e0 = __expf(zl - m);
    float s0 = e0;
#pragma unroll
    for (int off = 1; off <= 8; off <<= 1) s0 += __shfl_xor(s0, off, 64);
    zl -= m + __logf(s0);

    // loss5 term
    float m3 = zl;
#pragma unroll
    for (int off = 1; off <= 8; off <<= 1) m3 = fmaxf(m3, __shfl_xor(m3, off, 64));
    float e3 = __expf(zl - m3);
    float s3 = e3;
#pragma unroll
    for (int off = 1; off <= 8; off <<= 1) s3 += __shfl_xor(s3, off, 64);
    float l5 = m3 + __logf(s3);

    // ---- sampling part ----
    const float invT = fast_rcp(temperature[0]);
    const float zl_l = zl;
    const float tl_l = theta_logits[kd];
    const float lset = lsetp[0];

    const float em = enc_mu_g[(size_t)n * XD + d];
    const float es = enc_sig_g[(size_t)n * XD + d];
    const float inv_es = fast_rcp(es);
    const float log_es = __logf(es);
    const float em_ie = inv_es * em;

    float mu[KK], Sg[KK], tm[KK], ts[KK], pm[KK], ps[KK];
#pragma unroll
    for (int k = 0; k < KK; ++k) {
        float4 tb = tab4[k * XD + d];     // {phi_mu, phi_sig, th_mu, th_sig}
        pm[k] = tb.x; ps[k] = tb.y; tm[k] = tb.z; ts[k] = tb.w;
        float ig = fast_rcp(tb.y);
        Sg[k] = fast_rcp(inv_es + ig);
        mu[k] = Sg[k] * fmaf(ig, tb.x, em_ie);
    }

    // gumbel: 4 samples per pass; lane = (sgrp = g, k = kd)
    float eP[3];
    float esc = 0.f;
#pragma unroll
    for (int p = 0; p < 3; ++p) {
        int sp = p * 4 + g;
        int spc = sp < SS ? sp : 0;       // clamp (masked below)
        float u = u_noise[((size_t)n * SS + spc) * KK + kd];
        float lg = (zl_l - __logf(-__logf(u))) * invT;
        float mg = lg;
        mg = fmaxf(mg, __shfl_xor(mg, 1, 64));
        mg = fmaxf(mg, __shfl_xor(mg, 2, 64));
        mg = fmaxf(mg, __shfl_xor(mg, 4, 64));
        mg = fmaxf(mg, __shfl_xor(mg, 8, 64));
        float e = __expf(lg - mg);
        float zs = e;
        zs += __shfl_xor(zs, 1, 64);
        zs += __shfl_xor(zs, 2, 64);
        zs += __shfl_xor(zs, 4, 64);
        zs += __shfl_xor(zs, 8, 64);
        e *= fast_rcp(zs);                 // normalized weight
        eP[p] = e;
        if (sp < SS) esc = fmaf(e, tl_l - zl_l, esc);
    }

    float r_acc = 0.f;
    const float* erow = eps_noise + (size_t)n * SS * XD + d;
    unsigned short* xrow = x_bf16 + (size_t)n * SS * XD + d;

#pragma unroll
    for (int s = 0; s < SS; ++s) {
        const int p = s >> 2, L = (s & 3) * 16;
        float ms = 0.f, Ssum = 0.f, tmu = 0.f, tsig = 0.f, pmu = 0.f, psig = 0.f;
#pragma unroll
        for (int k = 0; k < KK; ++k) {
            float ek = bcast(eP[p], L + k);
            ms   = fmaf(ek, mu[k], ms);
            Ssum = fmaf(ek, Sg[k], Ssum);
            tmu  = fmaf(ek, tm[k], tmu);
            tsig = fmaf(ek, ts[k], tsig);
            pmu  = fmaf(ek, pm[k], pmu);
            psig = fmaf(ek, ps[k], psig);
        }
        float ep = erow[s * XD];
        float x = fmaf(__builtin_amdgcn_sqrtf(Ssum), ep, ms);
        xrow[s * XD] = f32_to_bf16(x);

        float de  = (x - em) * inv_es;
        float rts = fast_rcp(tsig);
        float dt2 = (x - tmu) * rts;
        float dp  = (x - pmu) * fast_rcp(psig);
        r_acc += 0.5f * (de * de - dt2 * dt2 + dp * dp) + __logf(psig * rts);
    }

    r_acc = fmaf((float)SS, log_es, r_acc);
    r_acc += esc;
    r_acc = wave_sum(r_acc);

    const float C234 = 0.5f * XD * 1.8378770664093453f;
    float total = r_acc + (float)SS * (C234 - lset);

    if (d == 0) { red234[wv] = total; red5[wv] = l5; }
    __syncthreads();
    if (threadIdx.x == 0) {
        atomicAdd(slots + (blockIdx.x & 63),
                  (double)(red234[0] + red234[1] + red234[2] + red234[3]));
        atomicAdd(slots + 64 + (blockIdx.x & 63),
                  (double)(red5[0] + red5[1] + red5[2] + red5[3]));
    }
}

// ---------------- Kernel 3: decoder via bf16 MFMA + fused loss1 ----------------
// grid dim3(NS/128, YD/64); block 256 = 4 waves; wave tile 32 rows x 64 cols.
// Y prefetched BEFORE the MFMA sequence (latency hidden behind matrix work).
// Epilogue in log2 domain: sig = ln2*s2 with s2 = log2(1+2^(t*log2e)) + 1e-3/ln2;
// the ln2 factors fold into Cq = -0.5/ln2^2 and a single end correction.
__global__ __launch_bounds__(256) void decoder_mfma(
    const unsigned short* __restrict__ xb,
    const unsigned short* __restrict__ wmu_s,
    const unsigned short* __restrict__ wsg_s,
    const float* __restrict__ bd_mu, const float* __restrict__ bd_sig,
    const float* __restrict__ Y, double* __restrict__ slots1,
    unsigned int magicS)
{
    __shared__ float red[4];
    const int t = threadIdx.x;
    const int w = t >> 6;
    const int lane = t & 63;
    const int l16 = lane & 15;
    const int quad = lane >> 4;
    const int mb = blockIdx.x;
    const int nb = blockIdx.y;

    const int row0 = mb * 128 + w * 32;

    // ---- prefetch Y for both row-groups (independent of MFMA results) ----
    float Yv[2][4][4];
#pragma unroll
    for (int rg = 0; rg < 2; ++rg) {
        const int m_base = row0 + rg * 16 + quad * 4;
        unsigned int q10 = (unsigned int)(((unsigned long long)(unsigned int)m_base * magicS) >> 35);
        int rem = m_base - (int)q10 * 10;     // 0..9
#pragma unroll
        for (int r = 0; r < 4; ++r) {
            unsigned int ny = q10 + ((rem + r) >= 10 ? 1u : 0u);
            unsigned int iy = ny * YD + nb * 64 + l16;
#pragma unroll
            for (int tt = 0; tt < 4; ++tt) Yv[rg][r][tt] = Y[iy + tt * 16];
        }
    }

    short8 a[2][2];
#pragma unroll
    for (int rg = 0; rg < 2; ++rg) {
        const unsigned short* xp = xb + (size_t)(row0 + rg * 16 + l16) * XD + quad * 8;
        a[rg][0] = *(const short8*)xp;
        a[rg][1] = *(const short8*)(xp + 32);
    }

    f32x4 accmu[2][4], accsg[2][4];
#pragma unroll
    for (int tt = 0; tt < 4; ++tt) {
        int col = nb * 64 + tt * 16 + l16;
        float bm = bd_mu[col], bs = bd_sig[col];
#pragma unroll
        for (int rg = 0; rg < 2; ++rg) {
            accmu[rg][tt] = (f32x4){bm, bm, bm, bm};
            accsg[rg][tt] = (f32x4){bs, bs, bs, bs};
        }
    }

#pragma unroll
    for (int tt = 0; tt < 4; ++tt) {
        int tg = nb * 4 + tt;
        int boff = ((tg * 8 + quad) * 16 + l16) * 8;
        short8 b0 = *(const short8*)(wmu_s + boff);
        short8 b1 = *(const short8*)(wmu_s + boff + 512);
        short8 c0 = *(const short8*)(wsg_s + boff);
        short8 c1 = *(const short8*)(wsg_s + boff + 512);
#pragma unroll
        for (int rg = 0; rg < 2; ++rg) {
            accmu[rg][tt] = __builtin_amdgcn_mfma_f32_16x16x32_bf16(a[rg][0], b0, accmu[rg][tt], 0, 0, 0);
            accmu[rg][tt] = __builtin_amdgcn_mfma_f32_16x16x32_bf16(a[rg][1], b1, accmu[rg][tt], 0, 0, 0);
            accsg[rg][tt] = __builtin_amdgcn_mfma_f32_16x16x32_bf16(a[rg][0], c0, accsg[rg][tt], 0, 0, 0);
            accsg[rg][tt] = __builtin_amdgcn_mfma_f32_16x16x32_bf16(a[rg][1], c1, accsg[rg][tt], 0, 0, 0);
        }
    }

    const float LOG2E = 1.4426950408889634f;
    const float C2    = 0.0014426950408889634f;   // 1e-3 / ln2
    const float Cq    = -1.0406844905181233f;     // -0.5 / ln2^2
    const float LN2   = 0.6931471805599453f;
    // per-lane constant: 32 elements * (-ln(ln2)) = 32 * 0.36651292058166435
    const float CC    = 11.72841345861326f;

    float part_q = 0.f, part_l = 0.f;
#pragma unroll
    for (int rg = 0; rg < 2; ++rg) {
        float prod = 1.0f;
#pragma unroll
        for (int r = 0; r < 4; ++r) {
#pragma unroll
            for (int tt = 0; tt < 4; ++tt) {
                // s2 = log2(1 + 2^(t*log2e)) + 1e-3/ln2   (sig = ln2 * s2)
                float u  = hw_exp2(accsg[rg][tt][r] * LOG2E);
                float s2 = hw_log2(1.0f + u) + C2;
                float diff = (Yv[rg][r][tt] - accmu[rg][tt][r]) * fast_rcp(s2);
                part_q = fmaf(Cq * diff, diff, part_q);
                prod *= s2;
            }
            if (r & 1) {                  // batch log2 over 8 s2 (prod in [3e-20,1e8])
                part_l += hw_log2(prod);
                prod = 1.0f;
            }
        }
    }
    float part = fmaf(-LN2, part_l, part_q) + CC;
    part = wave_sum(part);
    if (lane == 0) red[w] = part;
    __syncthreads();
    if (t == 0) {
        atomicAdd(slots1 + ((blockIdx.y * gridDim.x + blockIdx.x) & 63),
                  (double)(red[0] + red[1] + red[2] + red[3]));
    }
}

// ---------------- Kernel 4: finalize ----------------
__global__ void finalize_kernel(const double* __restrict__ slots,
                                float* __restrict__ out, int NS, int S)
{
    double l234 = 0.0, l5 = 0.0, l1 = 0.0;
    for (int i = 0; i < 64; ++i) {
        l234 += slots[i];
        l5   += slots[64 + i];
        l1   += slots[128 + i];
    }
    l1 += (double)NS * (-0.5 * (double)YD * 1.8378770664093453);
    out[0] = (float)(-((l1 + l234) / (double)S + l5));
}

extern "C" void kernel_launch(void* const* d_in, const int* in_sizes, int n_in,
                              void* d_out, int out_size, void* d_ws, size_t ws_size,
                              hipStream_t stream) {
    const float* Y            = (const float*)d_in[0];
    const float* We_mu        = (const float*)d_in[1];
    const float* be_mu        = (const float*)d_in[2];
    const float* We_sig       = (const float*)d_in[3];
    const float* be_sig       = (const float*)d_in[4];
    const float* Wd_mu        = (const float*)d_in[5];
    const float* bd_mu        = (const float*)d_in[6];
    const float* Wd_sig       = (const float*)d_in[7];
    const float* bd_sig       = (const float*)d_in[8];
    const float* phi_mus      = (const float*)d_in[9];
    const float* phi_sigs     = (const float*)d_in[10];
    const float* phi_logits   = (const float*)d_in[11];
    const float* theta_mus    = (const float*)d_in[12];
    const float* theta_sigs   = (const float*)d_in[13];
    const float* theta_logits = (const float*)d_in[14];
    const float* u_noise      = (const float*)d_in[15];
    const float* eps_noise    = (const float*)d_in[16];
    const float* temperature  = (const float*)d_in[17];

    const int N = in_sizes[0] / YD;           // 8192
    const int S = in_sizes[15] / (N * KK);    // 10 (== SS)
    const int NS = N * S;
    const unsigned int magicS =
        (unsigned int)((((unsigned long long)1 << 35) + S - 1) / (unsigned long long)S);

    char* base = (char*)d_ws;
    double* slots = (double*)base;                       // 192 doubles (3 x 64)
    float* enc_mu  = (float*)(base + 2048);
    float* enc_sig = enc_mu + (size_t)N * XD;
    float* zlp     = enc_sig + (size_t)N * XD;           // (unused, layout kept)
    float4* tab4   = (float4*)(zlp + (size_t)N * KK);    // 1024 float4
    float* lsetp   = (float*)(tab4 + 1024);
    unsigned short* xb    = (unsigned short*)(lsetp + 16);
    unsigned short* wmu_s = xb + (size_t)NS * XD;
    unsigned short* wsg_s = wmu_s + 32768;
    unsigned short* wenc  = wsg_s + 32768;               // 2 x 32768

    hipMemsetAsync(slots, 0, 2048, stream);

    prep_kernel<<<517, 256, 0, stream>>>(Wd_mu, Wd_sig, We_mu, We_sig,
                                         phi_mus, phi_sigs, theta_mus,
                                         theta_sigs, theta_logits,
                                         wmu_s, wsg_s, wenc, tab4, lsetp);
    encoder_mfma<<<(N / 16) * 2, 256, 0, stream>>>(Y, wenc, be_mu, be_sig,
                                                   enc_mu, enc_sig);
    fused_sample_kernel<<<N / 4, 256, 0, stream>>>(enc_mu, enc_sig,
                                                   phi_mus, phi_sigs, phi_logits,
                                                   tab4, theta_logits, lsetp,
                                                   u_noise, eps_noise, temperature,
                                                   xb, slots);
    decoder_mfma<<<dim3(NS / 128, YD / 64), 256, 0, stream>>>(
        xb, wmu_s, wsg_s, bd_mu, bd_sig, Y, slots + 128, magicS);
    finalize_kernel<<<1, 1, 0, stream>>>(slots, (float*)d_out, NS, S);
}

// Round 13
// 194.559 us; speedup vs baseline: 1.0996x; 1.0341x over previous
//
#include <hip/hip_runtime.h>
#include <math.h>

#define YD 512
#define XD 64
#define KK 16
#define SS 10

typedef __attribute__((ext_vector_type(8))) short short8;
typedef __attribute__((ext_vector_type(4))) float f32x4;
typedef __attribute__((ext_vector_type(2))) float f32x2;

__device__ __forceinline__ float wave_sum(float v) {
#pragma unroll
    for (int off = 32; off > 0; off >>= 1) v += __shfl_xor(v, off, 64);
    return v;
}

__device__ __forceinline__ float fast_rcp(float x) {
    return __builtin_amdgcn_rcpf(x);
}

// base-2 HW transcendentals: v_exp_f32 computes 2^x, v_log_f32 computes log2(x)
__device__ __forceinline__ float hw_exp2(float x) {
    return __builtin_amdgcn_exp2f(x);
}
__device__ __forceinline__ float hw_log2(float x) {
    return __builtin_amdgcn_logf(x);
}

__device__ __forceinline__ float bcast(float v, int l) {
    return __uint_as_float((unsigned int)__builtin_amdgcn_readlane((int)__float_as_uint(v), l));
}

__device__ __forceinline__ float softplusf(float x) {
    return fmaxf(x, 0.0f) + __logf(1.0f + __expf(-fabsf(x)));
}

__device__ __forceinline__ unsigned short f32_to_bf16(float f) {
    union { float f; unsigned int u; } v; v.f = f;
    unsigned int r = v.u + 0x7fffu + ((v.u >> 16) & 1u);
    return (unsigned short)(r >> 16);
}

__device__ __forceinline__ unsigned int pack2_bf16(float a, float b) {
    unsigned int ua = __float_as_uint(a), ub = __float_as_uint(b);
    ua = (ua + 0x7fffu + ((ua >> 16) & 1u)) >> 16;
    ub = (ub + 0x7fffu + ((ub >> 16) & 1u)) & 0xffff0000u;
    return ua | ub;
}

// ---------------- Kernel 0: prep ----------------
__global__ __launch_bounds__(256) void prep_kernel(
    const float* __restrict__ Wd_mu, const float* __restrict__ Wd_sig,
    const float* __restrict__ We_mu, const float* __restrict__ We_sig,
    const float* __restrict__ phi_mus, const float* __restrict__ phi_sigs,
    const float* __restrict__ theta_mus, const float* __restrict__ theta_sigs,
    const float* __restrict__ theta_logits,
    unsigned short* __restrict__ wmu_s, unsigned short* __restrict__ wsg_s,
    unsigned short* __restrict__ wenc,
    float4* __restrict__ tab4, float* __restrict__ lsetp)
{
    int idx = blockIdx.x * 256 + threadIdx.x;
    if (idx < 65536) {
        int mat = idx >> 15;            // 0: mu, 1: sig
        int e = idx & 32767;
        int j = e & 7;
        int n = (e >> 3) & 15;
        int q = (e >> 7) & 7;
        int tg = e >> 10;
        int k = q * 8 + j;
        int col = tg * 16 + n;
        const float* W = mat ? Wd_sig : Wd_mu;
        unsigned short* o = mat ? wsg_s : wmu_s;
        o[e] = f32_to_bf16(W[k * YD + col]);
    } else if (idx < 131072) {
        int ii = idx - 65536;
        int mat = ii >> 15;             // 0: We_mu, 1: We_sig
        int e = ii & 32767;
        int j = e & 7;
        int n = (e >> 3) & 15;
        int q = (e >> 7) & 3;
        int ct = (e >> 9) & 3;
        int kt = e >> 11;
        int k = kt * 32 + q * 8 + j;    // 0..511
        int col = ct * 16 + n;          // 0..63
        const float* W = mat ? We_sig : We_mu;
        wenc[mat * 32768 + e] = f32_to_bf16(W[k * XD + col]);
    } else if (idx < 131072 + 1024) {
        int e = idx - 131072;
        float4 t;
        t.x = phi_mus[e];
        t.y = phi_sigs[e];
        t.z = theta_mus[e];
        t.w = theta_sigs[e];
        tab4[e] = t;
    } else if (idx == 131072 + 1024) {
        float mt = theta_logits[0];
        for (int k = 1; k < KK; ++k) mt = fmaxf(mt, theta_logits[k]);
        float st = 0.f;
        for (int k = 0; k < KK; ++k) st += __expf(theta_logits[k] - mt);
        lsetp[0] = mt + __logf(st);
    }
}

// ---------------- Kernel 1: encoder via bf16 MFMA ----------------
__global__ __launch_bounds__(256) void encoder_mfma(
    const float* __restrict__ Y,
    const unsigned short* __restrict__ wenc,  // [2][32768] swizzled bf16
    const float* __restrict__ be_mu, const float* __restrict__ be_sig,
    float* __restrict__ enc_mu, float* __restrict__ enc_sig)
{
    const int t = threadIdx.x;
    const int w = t >> 6, lane = t & 63, l16 = lane & 15, quad = lane >> 4;
    const int mat = blockIdx.x & 1;
    const int rt = blockIdx.x >> 1;            // 16-row tile
    const int row = rt * 16 + l16;
    const int ct = w;                          // col tile 0..3
    const unsigned short* Ws = wenc + mat * 32768;
    const float4* Yrow = (const float4*)(Y + (size_t)row * YD);

    const float* bias = mat ? be_sig : be_mu;
    float* outp = mat ? enc_sig : enc_mu;
    const int col = ct * 16 + l16;
    const float bv = bias[col];
    f32x4 acc = (f32x4){bv, bv, bv, bv};

#pragma unroll
    for (int kt = 0; kt < 16; ++kt) {
        float4 y0 = Yrow[kt * 8 + quad * 2];
        float4 y1 = Yrow[kt * 8 + quad * 2 + 1];
        union { short8 s; unsigned int u[4]; } a;
        a.u[0] = pack2_bf16(y0.x, y0.y);
        a.u[1] = pack2_bf16(y0.z, y0.w);
        a.u[2] = pack2_bf16(y1.x, y1.y);
        a.u[3] = pack2_bf16(y1.z, y1.w);
        short8 b = *(const short8*)(Ws + (((kt * 4 + ct) * 4 + quad) * 16 + l16) * 8);
        acc = __builtin_amdgcn_mfma_f32_16x16x32_bf16(a.s, b, acc, 0, 0, 0);
    }

    const int base_row = rt * 16 + quad * 4;
#pragma unroll
    for (int r = 0; r < 4; ++r) {
        float v = acc[r];
        if (mat) v = softplusf(v) + 1e-3f;
        outp[(size_t)(base_row + r) * XD + col] = v;
    }
}

// ---------------- Kernel 2: fused responsibilities + sampling + losses 2/3/4/5 ----------------
// one wave per n; mixture accumulators packed into f32x2 (v_pk_fma_f32)
__global__ __launch_bounds__(256, 3) void fused_sample_kernel(
    const float* __restrict__ enc_mu_g, const float* __restrict__ enc_sig_g,
    const float* __restrict__ phi_mus, const float* __restrict__ phi_sigs,
    const float* __restrict__ phi_logits, const float4* __restrict__ tab4,
    const float* __restrict__ theta_logits, const float* __restrict__ lsetp,
    const float* __restrict__ u_noise, const float* __restrict__ eps_noise,
    const float* __restrict__ temperature,
    unsigned short* __restrict__ x_bf16, double* __restrict__ slots)
{
    __shared__ float red234[4], red5[4];
    const int wv = threadIdx.x >> 6;
    const int n = blockIdx.x * 4 + wv;
    const int d = threadIdx.x & 63;
    const int kd = d & 15;
    const int g = d >> 4;

    // ---- responsibilities: lane = (g, kd); partial over dims g*16..g*16+15 ----
    const float4* em4 = (const float4*)(enc_mu_g + (size_t)n * XD + g * 16);
    const float4* es4 = (const float4*)(enc_sig_g + (size_t)n * XD + g * 16);
    const float4* pm4 = (const float4*)(phi_mus + kd * XD + g * 16);
    const float4* ps4 = (const float4*)(phi_sigs + kd * XD + g * 16);

    float part = 0.f;
#pragma unroll
    for (int q = 0; q < 4; ++q) {
        float4 emv = em4[q], esv = es4[q], pmv = pm4[q], psv = ps4[q];
        {
            float sd = esv.x + psv.x; float df = (emv.x - pmv.x) * fast_rcp(sd);
            part += fmaf(-0.5f * df, df, -__logf(sd));
        }
        {
            float sd = esv.y + psv.y; float df = (emv.y - pmv.y) * fast_rcp(sd);
            part += fmaf(-0.5f * df, df, -__logf(sd));
        }
        {
            float sd = esv.z + psv.z; float df = (emv.z - pmv.z) * fast_rcp(sd);
            part += fmaf(-0.5f * df, df, -__logf(sd));
        }
        {
            float sd = esv.w + psv.w; float df = (emv.w - pmv.w) * fast_rcp(sd);
            part += fmaf(-0.5f * df, df, -__logf(sd));
        }
    }
    part += __shfl_xor(part, 16, 64);
    part += __shfl_xor(part, 32, 64);
    float zl = part + phi_logits[kd];

    // log_softmax over k (lane-parallel within 16-groups; zl now 4x replicated)
    float m = zl;
#pragma unroll
    for (int off = 1; off <= 8; off <<= 1) m = fmaxf(m, __shfl_xor(m, off, 64));
    float e0 = __expf(zl - m);
    float s0 = e0;
#pragma unroll
    for (int off = 1; off <= 8; off <<= 1) s0 += __shfl_xor(s0, off, 64);
    zl -= m + __logf(s0);

    // loss5 term
    float m3 = zl;
#pragma unroll
    for (int off = 1; off <= 8; off <<= 1) m3 = fmaxf(m3, __shfl_xor(m3, off, 64));
    float e3 = __expf(zl - m3);
    float s3 = e3;
#pragma unroll
    for (int off = 1; off <= 8; off <<= 1) s3 += __shfl_xor(s3, off, 64);
    float l5 = m3 + __logf(s3);

    // ---- sampling part ----
    const float invT = fast_rcp(temperature[0]);
    const float zl_l = zl;
    const float tl_l = theta_logits[kd];
    const float lset = lsetp[0];

    const float em = enc_mu_g[(size_t)n * XD + d];
    const float es = enc_sig_g[(size_t)n * XD + d];
    const float inv_es = fast_rcp(es);
    const float log_es = __logf(es);
    const float em_ie = inv_es * em;

    // table triplets as f32x2 pairs: {mu,Sg}, {tm,ts}, {pm,ps}
    f32x2 mS[KK], tt2[KK], pp2[KK];
#pragma unroll
    for (int k = 0; k < KK; ++k) {
        float4 tb = tab4[k * XD + d];     // {phi_mu, phi_sig, th_mu, th_sig}
        float ig = fast_rcp(tb.y);
        float Sgk = fast_rcp(inv_es + ig);
        float muk = Sgk * fmaf(ig, tb.x, em_ie);
        mS[k]  = (f32x2){muk, Sgk};
        tt2[k] = (f32x2){tb.z, tb.w};
        pp2[k] = (f32x2){tb.x, tb.y};
    }

    // gumbel: 4 samples per pass; lane = (sgrp = g, k = kd)
    float eP[3];
    float esc = 0.f;
#pragma unroll
    for (int p = 0; p < 3; ++p) {
        int sp = p * 4 + g;
        int spc = sp < SS ? sp : 0;       // clamp (masked below)
        float u = u_noise[((size_t)n * SS + spc) * KK + kd];
        float lg = (zl_l - __logf(-__logf(u))) * invT;
        float mg = lg;
        mg = fmaxf(mg, __shfl_xor(mg, 1, 64));
        mg = fmaxf(mg, __shfl_xor(mg, 2, 64));
        mg = fmaxf(mg, __shfl_xor(mg, 4, 64));
        mg = fmaxf(mg, __shfl_xor(mg, 8, 64));
        float e = __expf(lg - mg);
        float zs = e;
        zs += __shfl_xor(zs, 1, 64);
        zs += __shfl_xor(zs, 2, 64);
        zs += __shfl_xor(zs, 4, 64);
        zs += __shfl_xor(zs, 8, 64);
        e *= fast_rcp(zs);                 // normalized weight
        eP[p] = e;
        if (sp < SS) esc = fmaf(e, tl_l - zl_l, esc);
    }

    float r_acc = 0.f;
    const float* erow = eps_noise + (size_t)n * SS * XD + d;
    unsigned short* xrow = x_bf16 + (size_t)n * SS * XD + d;

#pragma unroll
    for (int s = 0; s < SS; ++s) {
        const int p = s >> 2, L = (s & 3) * 16;
        f32x2 a0 = (f32x2){0.f, 0.f};
        f32x2 a1 = (f32x2){0.f, 0.f};
        f32x2 a2 = (f32x2){0.f, 0.f};
#pragma unroll
        for (int k = 0; k < KK; ++k) {
            float ek = bcast(eP[p], L + k);
            f32x2 ev = (f32x2){ek, ek};
            a0 = a0 + ev * mS[k];          // v_pk_fma_f32
            a1 = a1 + ev * tt2[k];
            a2 = a2 + ev * pp2[k];
        }
        float ms = a0.x, Ssum = a0.y;
        float tmu = a1.x, tsig = a1.y;
        float pmu = a2.x, psig = a2.y;

        float ep = erow[s * XD];
        float x = fmaf(__builtin_amdgcn_sqrtf(Ssum), ep, ms);
        xrow[s * XD] = f32_to_bf16(x);

        float de  = (x - em) * inv_es;
        float rts = fast_rcp(tsig);
        float dt2 = (x - tmu) * rts;
        float dp  = (x - pmu) * fast_rcp(psig);
        r_acc += 0.5f * (de * de - dt2 * dt2 + dp * dp) + __logf(psig * rts);
    }

    r_acc = fmaf((float)SS, log_es, r_acc);
    r_acc += esc;
    r_acc = wave_sum(r_acc);

    const float C234 = 0.5f * XD * 1.8378770664093453f;
    float total = r_acc + (float)SS * (C234 - lset);

    if (d == 0) { red234[wv] = total; red5[wv] = l5; }
    __syncthreads();
    if (threadIdx.x == 0) {
        atomicAdd(slots + (blockIdx.x & 63),
                  (double)(red234[0] + red234[1] + red234[2] + red234[3]));
        atomicAdd(slots + 64 + (blockIdx.x & 63),
                  (double)(red5[0] + red5[1] + red5[2] + red5[3]));
    }
}

// ---------------- Kernel 3: decoder via bf16 MFMA + fused loss1 ----------------
// grid dim3(NS/128, YD/64); block 256 = 4 waves; wave tile 32 rows x 64 cols.
// Epilogue full-rate ops packed over the rg=0/1 pair (v_pk_* f32).
__global__ __launch_bounds__(256) void decoder_mfma(
    const unsigned short* __restrict__ xb,
    const unsigned short* __restrict__ wmu_s,
    const unsigned short* __restrict__ wsg_s,
    const float* __restrict__ bd_mu, const float* __restrict__ bd_sig,
    const float* __restrict__ Y, double* __restrict__ slots1,
    unsigned int magicS)
{
    __shared__ float red[4];
    const int t = threadIdx.x;
    const int w = t >> 6;
    const int lane = t & 63;
    const int l16 = lane & 15;
    const int quad = lane >> 4;
    const int mb = blockIdx.x;
    const int nb = blockIdx.y;

    const int row0 = mb * 128 + w * 32;

    // ---- prefetch Y for both row-groups (independent of MFMA results) ----
    float Yv[2][4][4];
#pragma unroll
    for (int rg = 0; rg < 2; ++rg) {
        const int m_base = row0 + rg * 16 + quad * 4;
        unsigned int q10 = (unsigned int)(((unsigned long long)(unsigned int)m_base * magicS) >> 35);
        int rem = m_base - (int)q10 * 10;     // 0..9
#pragma unroll
        for (int r = 0; r < 4; ++r) {
            unsigned int ny = q10 + ((rem + r) >= 10 ? 1u : 0u);
            unsigned int iy = ny * YD + nb * 64 + l16;
#pragma unroll
            for (int tt = 0; tt < 4; ++tt) Yv[rg][r][tt] = Y[iy + tt * 16];
        }
    }

    short8 a[2][2];
#pragma unroll
    for (int rg = 0; rg < 2; ++rg) {
        const unsigned short* xp = xb + (size_t)(row0 + rg * 16 + l16) * XD + quad * 8;
        a[rg][0] = *(const short8*)xp;
        a[rg][1] = *(const short8*)(xp + 32);
    }

    f32x4 accmu[2][4], accsg[2][4];
#pragma unroll
    for (int tt = 0; tt < 4; ++tt) {
        int col = nb * 64 + tt * 16 + l16;
        float bm = bd_mu[col], bs = bd_sig[col];
#pragma unroll
        for (int rg = 0; rg < 2; ++rg) {
            accmu[rg][tt] = (f32x4){bm, bm, bm, bm};
            accsg[rg][tt] = (f32x4){bs, bs, bs, bs};
        }
    }

#pragma unroll
    for (int tt = 0; tt < 4; ++tt) {
        int tg = nb * 4 + tt;
        int boff = ((tg * 8 + quad) * 16 + l16) * 8;
        short8 b0 = *(const short8*)(wmu_s + boff);
        short8 b1 = *(const short8*)(wmu_s + boff + 512);
        short8 c0 = *(const short8*)(wsg_s + boff);
        short8 c1 = *(const short8*)(wsg_s + boff + 512);
#pragma unroll
        for (int rg = 0; rg < 2; ++rg) {
            accmu[rg][tt] = __builtin_amdgcn_mfma_f32_16x16x32_bf16(a[rg][0], b0, accmu[rg][tt], 0, 0, 0);
            accmu[rg][tt] = __builtin_amdgcn_mfma_f32_16x16x32_bf16(a[rg][1], b1, accmu[rg][tt], 0, 0, 0);
            accsg[rg][tt] = __builtin_amdgcn_mfma_f32_16x16x32_bf16(a[rg][0], c0, accsg[rg][tt], 0, 0, 0);
            accsg[rg][tt] = __builtin_amdgcn_mfma_f32_16x16x32_bf16(a[rg][1], c1, accsg[rg][tt], 0, 0, 0);
        }
    }

    const float LOG2E = 1.4426950408889634f;
    const float C2    = 0.0014426950408889634f;   // 1e-3 / ln2
    const float Cq    = -1.0406844905181233f;     // -0.5 / ln2^2
    const float LN2   = 0.6931471805599453f;
    // per-lane constant: 32 elements * (-ln(ln2))
    const float CC    = 11.72841345861326f;

    f32x2 pq = (f32x2){0.f, 0.f};
    f32x2 pl = (f32x2){0.f, 0.f};
    f32x2 prod = (f32x2){1.f, 1.f};
#pragma unroll
    for (int r = 0; r < 4; ++r) {
#pragma unroll
        for (int tt = 0; tt < 4; ++tt) {
            f32x2 acs = (f32x2){accsg[0][tt][r], accsg[1][tt][r]};
            f32x2 acm = (f32x2){accmu[0][tt][r], accmu[1][tt][r]};
            f32x2 yv  = (f32x2){Yv[0][r][tt], Yv[1][r][tt]};
            f32x2 te  = acs * LOG2E;                       // v_pk_mul
            f32x2 u2;
            u2.x = hw_exp2(te.x);
            u2.y = hw_exp2(te.y);
            f32x2 up = u2 + 1.0f;                          // v_pk_add
            f32x2 s2;
            s2.x = hw_log2(up.x);
            s2.y = hw_log2(up.y);
            s2 = s2 + C2;                                  // v_pk_add
            f32x2 rs;
            rs.x = fast_rcp(s2.x);
            rs.y = fast_rcp(s2.y);
            f32x2 diff = (yv - acm) * rs;                  // pk_sub + pk_mul
            pq = pq + (Cq * diff) * diff;                  // pk_mul + pk_fma
            prod = prod * s2;                              // pk_mul
        }
        if (r & 1) {               // batch log2 over 8 s2 per rg-half
            pl.x += hw_log2(prod.x);
            pl.y += hw_log2(prod.y);
            prod = (f32x2){1.f, 1.f};
        }
    }
    float part = fmaf(-LN2, pl.x + pl.y, pq.x + pq.y) + CC;
    part = wave_sum(part);
    if (lane == 0) red[w] = part;
    __syncthreads();
    if (t == 0) {
        atomicAdd(slots1 + ((blockIdx.y * gridDim.x + blockIdx.x) & 63),
                  (double)(red[0] + red[1] + red[2] + red[3]));
    }
}

// ---------------- Kernel 4: finalize ----------------
__global__ void finalize_kernel(const double* __restrict__ slots,
                                float* __restrict__ out, int NS, int S)
{
    double l234 = 0.0, l5 = 0.0, l1 = 0.0;
    for (int i = 0; i < 64; ++i) {
        l234 += slots[i];
        l5   += slots[64 + i];
        l1   += slots[128 + i];
    }
    l1 += (double)NS * (-0.5 * (double)YD * 1.8378770664093453);
    out[0] = (float)(-((l1 + l234) / (double)S + l5));
}

extern "C" void kernel_launch(void* const* d_in, const int* in_sizes, int n_in,
                              void* d_out, int out_size, void* d_ws, size_t ws_size,
                              hipStream_t stream) {
    const float* Y            = (const float*)d_in[0];
    const float* We_mu        = (const float*)d_in[1];
    const float* be_mu        = (const float*)d_in[2];
    const float* We_sig       = (const float*)d_in[3];
    const float* be_sig       = (const float*)d_in[4];
    const float* Wd_mu        = (const float*)d_in[5];
    const float* bd_mu        = (const float*)d_in[6];
    const float* Wd_sig       = (const float*)d_in[7];
    const float* bd_sig       = (const float*)d_in[8];
    const float* phi_mus      = (const float*)d_in[9];
    const float* phi_sigs     = (const float*)d_in[10];
    const float* phi_logits   = (const float*)d_in[11];
    const float* theta_mus    = (const float*)d_in[12];
    const float* theta_sigs   = (const float*)d_in[13];
    const float* theta_logits = (const float*)d_in[14];
    const float* u_noise      = (const float*)d_in[15];
    const float* eps_noise    = (const float*)d_in[16];
    const float* temperature  = (const float*)d_in[17];

    const int N = in_sizes[0] / YD;           // 8192
    const int S = in_sizes[15] / (N * KK);    // 10 (== SS)
    const int NS = N * S;
    const unsigned int magicS =
        (unsigned int)((((unsigned long long)1 << 35) + S - 1) / (unsigned long long)S);

    char* base = (char*)d_ws;
    double* slots = (double*)base;                       // 192 doubles (3 x 64)
    float* enc_mu  = (float*)(base + 2048);
    float* enc_sig = enc_mu + (size_t)N * XD;
    float* zlp     = enc_sig + (size_t)N * XD;           // (unused, layout kept)
    float4* tab4   = (float4*)(zlp + (size_t)N * KK);    // 1024 float4
    float* lsetp   = (float*)(tab4 + 1024);
    unsigned short* xb    = (unsigned short*)(lsetp + 16);
    unsigned short* wmu_s = xb + (size_t)NS * XD;
    unsigned short* wsg_s = wmu_s + 32768;
    unsigned short* wenc  = wsg_s + 32768;               // 2 x 32768

    hipMemsetAsync(slots, 0, 2048, stream);

    prep_kernel<<<517, 256, 0, stream>>>(Wd_mu, Wd_sig, We_mu, We_sig,
                                         phi_mus, phi_sigs, theta_mus,
                                         theta_sigs, theta_logits,
                                         wmu_s, wsg_s, wenc, tab4, lsetp);
    encoder_mfma<<<(N / 16) * 2, 256, 0, stream>>>(Y, wenc, be_mu, be_sig,
                                                   enc_mu, enc_sig);
    fused_sample_kernel<<<N / 4, 256, 0, stream>>>(enc_mu, enc_sig,
                                                   phi_mus, phi_sigs, phi_logits,
                                                   tab4, theta_logits, lsetp,
                                                   u_noise, eps_noise, temperature,
                                                   xb, slots);
    decoder_mfma<<<dim3(NS / 128, YD / 64), 256, 0, stream>>>(
        xb, wmu_s, wsg_s, bd_mu, bd_sig, Y, slots + 128, magicS);
    finalize_kernel<<<1, 1, 0, stream>>>(slots, (float*)d_out, NS, S);
}